// Round 1
// baseline (3879.456 us; speedup 1.0000x reference)
//
#include <hip/hip_runtime.h>

// Fused ST-attention block for MI355X (gfx950), fp32 baseline.
// One block per (n,t); 512 threads; ~157KB static LDS; 1 block/CU.
//
// N=64 C=256 T=120 V=25 H=8 HD=32 K=5 MAXHOP=5

#define N_ 64
#define C_ 256
#define T_ 120
#define V_ 25
#define H_ 8
#define HD_ 32
#define K_ 5

#define TV_ (T_*V_)      // 3000
#define CTV_ (C_*TV_)    // 768000

// ---- LDS layout (float offsets) ----
#define XT_S 268         // x^T / o^T row stride (16B-aligned rows, bank-spread)
#define QK_S 28          // q/k row stride (112B, 16B-aligned)
#define VB_S 36          // v row stride (144B, 16B-aligned)
#define AT_S 28          // attn row stride
#define OFF_XT 0                    // [25][268]  x -> xn -> o^T   (6700)
#define OFF_Z 6700                  // [256][5]   z               (1280)
#define OFF_QB 7980                 // [256][28]  q  (h*32+c major)(7168)
#define OFF_KB 15148                // [256][28]  e then k+e       (7168)
#define OFF_VB 22316                // [8][25][36] v (h,m,c)       (7200)
#define OFF_AT 29516                // [8][25][28] attn/mix        (5600)
#define OFF_QR 35116                // [8][25][5]  q.rpe           (1000)
#define OFF_BIAS 36116              // [8][25]     w1.e            (200)
#define OFF_MU 36316                // [25] mean (pad 32)
#define OFF_RS 36348                // [25] rstd (pad 32)
#define OFF_INV 36380               // [5]  1/colsum(jl) (pad 8)
#define OFF_JL 36388                // [25][5] joint_label (pad->36516)
#define OFF_W1 36516                // [8][32]
#define OFF_RPE 36772               // [5][256]
#define OFF_PS 38052                // [8][32] LN partial sums
#define OFF_PSS 38308               // [8][32] LN partial sumsq
#define OFF_HOPS 38564              // int [25][25] (625 -> pad 39192)
#define SMEM_N 39192                // 156,768 bytes

__global__ __launch_bounds__(512, 2) void fused_sttr(
    const float* __restrict__ x, const float* __restrict__ jl,
    const int* __restrict__ hops, const float* __restrict__ n1w,
    const float* __restrict__ n1b, const float* __restrict__ qw,
    const float* __restrict__ kvw, const float* __restrict__ pjw,
    const float* __restrict__ pjb, const float* __restrict__ rpe,
    const float* __restrict__ w1, const float* __restrict__ outer,
    const float* __restrict__ alpha, const float* __restrict__ pew,
    float* __restrict__ out)
{
    __shared__ float sm[SMEM_N];
    int* hopsS = (int*)(sm + OFF_HOPS);
    const int tid = threadIdx.x;
    const int bid = blockIdx.x;
    const int n = bid / T_;
    const int t = bid - n * T_;
    const int xbase = n * CTV_ + t * V_;   // + c*3000 + v

    // ---- P0: stage tables + x slice (transposed) ----
    for (int i = tid; i < V_*K_; i += 512) sm[OFF_JL + i] = jl[i];
    for (int i = tid; i < V_*V_; i += 512) hopsS[i] = hops[i];
    for (int i = tid; i < H_*HD_; i += 512) sm[OFF_W1 + i] = w1[i];
    for (int i = tid; i < 5*C_; i += 512) sm[OFF_RPE + i] = rpe[i];
    for (int i = tid; i < C_*V_; i += 512) {
        int c = i / V_, v = i - c * V_;
        sm[OFF_XT + v * XT_S + c] = x[xbase + c * TV_ + v];
    }
    __syncthreads();

    // ---- P1: jl column inv-sums (5 thr) | LN partial sums (200 thr) ----
    if (tid < K_) {
        float s = 0.f;
        for (int v = 0; v < V_; ++v) s += sm[OFF_JL + v*K_ + tid];
        sm[OFF_INV + tid] = 1.0f / s;
    } else if (tid >= 256 && tid < 456) {
        int i = tid - 256;
        int v = i % V_, p = i / V_;
        const float* row = &sm[OFF_XT + v*XT_S + p*32];
        float s = 0.f, ss = 0.f;
        #pragma unroll
        for (int j = 0; j < 32; ++j) { float xx = row[j]; s += xx; ss += xx*xx; }
        sm[OFF_PS  + p*32 + v] = s;
        sm[OFF_PSS + p*32 + v] = ss;
    }
    __syncthreads();

    // ---- P2: z = x @ (jl/colsum) (256 thr) | mu/rstd (25 thr) ----
    if (tid < C_) {
        float a0=0,a1=0,a2=0,a3=0,a4=0;
        #pragma unroll
        for (int v = 0; v < V_; ++v) {
            float xv = sm[OFF_XT + v*XT_S + tid];
            const float* j5 = &sm[OFF_JL + v*K_];
            a0 += xv*j5[0]; a1 += xv*j5[1]; a2 += xv*j5[2];
            a3 += xv*j5[3]; a4 += xv*j5[4];
        }
        float* zr = &sm[OFF_Z + tid*K_];
        zr[0]=a0*sm[OFF_INV+0]; zr[1]=a1*sm[OFF_INV+1]; zr[2]=a2*sm[OFF_INV+2];
        zr[3]=a3*sm[OFF_INV+3]; zr[4]=a4*sm[OFF_INV+4];
    } else if (tid < C_ + V_) {
        int v = tid - C_;
        float s=0.f, ss=0.f;
        #pragma unroll
        for (int p = 0; p < 8; ++p) { s += sm[OFF_PS+p*32+v]; ss += sm[OFF_PSS+p*32+v]; }
        float mu = s * (1.0f/256.0f);
        float var = ss * (1.0f/256.0f) - mu*mu;
        sm[OFF_MU + v] = mu;
        sm[OFF_RS + v] = rsqrtf(var + 1e-5f);
    }
    __syncthreads();

    // ---- P3: z2 = pe_w@z, e = z2@jl^T -> KB (256 thr) | normalize x in place (256 thr) ----
    if (tid < C_) {
        const float* wrow = pew + tid * C_;
        float b0=0,b1=0,b2=0,b3=0,b4=0;
        for (int c4 = 0; c4 < C_; c4 += 4) {
            float4 w4 = *(const float4*)(wrow + c4);
            float zz[20];
            *(float4*)&zz[0]  = *(const float4*)&sm[OFF_Z + c4*K_];
            *(float4*)&zz[4]  = *(const float4*)&sm[OFF_Z + c4*K_ + 4];
            *(float4*)&zz[8]  = *(const float4*)&sm[OFF_Z + c4*K_ + 8];
            *(float4*)&zz[12] = *(const float4*)&sm[OFF_Z + c4*K_ + 12];
            *(float4*)&zz[16] = *(const float4*)&sm[OFF_Z + c4*K_ + 16];
            b0 += w4.x*zz[0] + w4.y*zz[5]  + w4.z*zz[10] + w4.w*zz[15];
            b1 += w4.x*zz[1] + w4.y*zz[6]  + w4.z*zz[11] + w4.w*zz[16];
            b2 += w4.x*zz[2] + w4.y*zz[7]  + w4.z*zz[12] + w4.w*zz[17];
            b3 += w4.x*zz[3] + w4.y*zz[8]  + w4.z*zz[13] + w4.w*zz[18];
            b4 += w4.x*zz[4] + w4.y*zz[9]  + w4.z*zz[14] + w4.w*zz[19];
        }
        float* kbr = &sm[OFF_KB + tid*QK_S];
        #pragma unroll
        for (int v = 0; v < V_; ++v) {
            const float* j5 = &sm[OFF_JL + v*K_];
            kbr[v] = b0*j5[0] + b1*j5[1] + b2*j5[2] + b3*j5[3] + b4*j5[4];
        }
    } else {
        for (int i = tid - C_; i < C_*V_; i += 256) {
            int c = i / V_, v = i - c*V_;
            float xx = sm[OFF_XT + v*XT_S + c];
            sm[OFF_XT + v*XT_S + c] = (xx - sm[OFF_MU+v]) * sm[OFF_RS+v] * n1w[c] + n1b[c];
        }
    }
    __syncthreads();

    // ---- P4: bias[h][m] = w1 . e  (reads KB==e, before k accumulates) ----
    if (tid < H_*V_) {
        int h = tid / V_, m = tid - h*V_;
        float s = 0.f;
        #pragma unroll
        for (int c = 0; c < HD_; ++c)
            s += sm[OFF_W1 + h*HD_ + c] * sm[OFF_KB + (h*HD_ + c)*QK_S + m];
        sm[OFF_BIAS + h*V_ + m] = s;
    }
    __syncthreads();

    // ---- P5: QKV GEMM [768x256] @ xn[256x25]; k accumulates onto e ----
    {
        const int rg = tid >> 3;               // 0..63 -> 12 rows each
        const int vg = tid & 7;                // v-groups {4,3,3,3,3,3,3,3}
        const int r0 = rg * 12;
        const int v0 = (vg == 0) ? 0 : (3*vg + 1);
        const int nv = (vg == 0) ? 4 : 3;
        const float* wp[12];
        #pragma unroll
        for (int j = 0; j < 12; ++j) {
            int r = r0 + j;
            wp[j] = (r < C_) ? (qw + r*C_) : (kvw + (r - C_)*C_);
        }
        float acc[12][4];
        #pragma unroll
        for (int j = 0; j < 12; ++j)
            #pragma unroll
            for (int vv = 0; vv < 4; ++vv) acc[j][vv] = 0.f;
        for (int c4 = 0; c4 < C_; c4 += 4) {
            float4 xv[4];
            #pragma unroll
            for (int vv = 0; vv < 4; ++vv)   // row 25 read = harmless LDS garbage
                xv[vv] = *(const float4*)&sm[OFF_XT + (v0+vv)*XT_S + c4];
            #pragma unroll
            for (int j = 0; j < 12; ++j) {
                float4 w4 = *(const float4*)(wp[j] + c4);
                #pragma unroll
                for (int vv = 0; vv < 4; ++vv)
                    acc[j][vv] += w4.x*xv[vv].x + w4.y*xv[vv].y
                                + w4.z*xv[vv].z + w4.w*xv[vv].w;
            }
        }
        #pragma unroll
        for (int j = 0; j < 12; ++j) {
            int r = r0 + j;
            #pragma unroll
            for (int vv = 0; vv < 4; ++vv) {
                if (vv < nv) {
                    int v = v0 + vv;
                    float a = acc[j][vv];
                    if (r < C_)          sm[OFF_QB + r*QK_S + v] = a;
                    else if (r < 2*C_)   sm[OFF_KB + (r - C_)*QK_S + v] += a;
                    else {
                        int d = r - 2*C_;
                        sm[OFF_VB + ((d >> 5)*V_ + v)*VB_S + (d & 31)] = a;
                    }
                }
            }
        }
    }
    __syncthreads();

    // ---- P6: qr[h][n][hop] = q . rpe ----
    for (int i = tid; i < H_*V_*K_; i += 512) {
        int h = i / (V_*K_);
        int rem = i - h*(V_*K_);
        int nq = rem / K_;
        int hop = rem - nq*K_;
        const float* rp = &sm[OFF_RPE + hop*C_ + h*HD_];
        float s = 0.f;
        #pragma unroll
        for (int c = 0; c < HD_; ++c)
            s += sm[OFF_QB + (h*HD_ + c)*QK_S + nq] * rp[c];
        sm[OFF_QR + (h*V_ + nq)*K_ + hop] = s;
    }
    __syncthreads();

    // ---- P7: attn scores, 4x4 register tiles (392 thr) ----
    if (tid < 392) {
        int h = tid / 49;
        int r = tid - h*49;
        int qg = r / 7, mg = r - qg*7;
        int q0 = qg*4, m0 = mg*4;
        float acc[4][4];
        #pragma unroll
        for (int i=0;i<4;++i)
            #pragma unroll
            for (int j=0;j<4;++j) acc[i][j]=0.f;
        for (int c = 0; c < HD_; ++c) {
            float4 q4 = *(const float4*)&sm[OFF_QB + (h*HD_+c)*QK_S + q0];
            float4 k4 = *(const float4*)&sm[OFF_KB + (h*HD_+c)*QK_S + m0];
            float qa[4] = {q4.x, q4.y, q4.z, q4.w};
            float ka[4] = {k4.x, k4.y, k4.z, k4.w};
            #pragma unroll
            for (int i=0;i<4;++i)
                #pragma unroll
                for (int j=0;j<4;++j) acc[i][j] += qa[i]*ka[j];
        }
        #pragma unroll
        for (int i = 0; i < 4; ++i) {
            int nq = q0 + i;
            if (nq < V_) {
                #pragma unroll
                for (int j = 0; j < 4; ++j) {
                    int m = m0 + j;
                    if (m < V_) {
                        int hop = hopsS[nq*V_ + m];
                        float val = acc[i][j]
                                  + sm[OFF_QR + (h*V_+nq)*K_ + hop]
                                  + sm[OFF_BIAS + h*V_ + m];
                        sm[OFF_AT + (h*V_+nq)*AT_S + m] = val;
                    }
                }
            }
        }
    }
    __syncthreads();

    // ---- P8: softmax + mix = alpha*p + outer  (200 thr) ----
    if (tid < H_*V_) {
        int h = tid / V_, nq = tid - h*V_;
        float* row = &sm[OFF_AT + (h*V_+nq)*AT_S];
        const float sc = 0.17677669529663688f;  // 32^-0.5
        float ev[25];
        float mx = -1e30f;
        #pragma unroll
        for (int j = 0; j < V_; ++j) { ev[j] = row[j]*sc; mx = fmaxf(mx, ev[j]); }
        float s = 0.f;
        #pragma unroll
        for (int j = 0; j < V_; ++j) { ev[j] = __expf(ev[j]-mx); s += ev[j]; }
        float inv = alpha[0] / s;
        const float* ob = outer + (h*V_ + nq)*V_;
        #pragma unroll
        for (int j = 0; j < V_; ++j) row[j] = ev[j]*inv + ob[j];
    }
    __syncthreads();

    // ---- P9: o = mix @ v -> o^T into XT (xn dead)  (160 thr) ----
    if (tid < 160) {
        int h = tid / 20;
        int r = tid - h*20;
        int ng = r >> 2, cg = r & 3;
        int n0 = ng*5, c0 = cg*8;
        float acc[5][8];
        #pragma unroll
        for (int i=0;i<5;++i)
            #pragma unroll
            for (int e=0;e<8;++e) acc[i][e]=0.f;
        for (int m = 0; m < V_; ++m) {
            float4 va = *(const float4*)&sm[OFF_VB + (h*V_+m)*VB_S + c0];
            float4 vb = *(const float4*)&sm[OFF_VB + (h*V_+m)*VB_S + c0 + 4];
            float vv8[8] = {va.x,va.y,va.z,va.w,vb.x,vb.y,vb.z,vb.w};
            #pragma unroll
            for (int i = 0; i < 5; ++i) {
                float mixv = sm[OFF_AT + (h*V_+n0+i)*AT_S + m];
                #pragma unroll
                for (int e = 0; e < 8; ++e) acc[i][e] += mixv * vv8[e];
            }
        }
        #pragma unroll
        for (int i = 0; i < 5; ++i) {
            float4 wa = {acc[i][0],acc[i][1],acc[i][2],acc[i][3]};
            float4 wb = {acc[i][4],acc[i][5],acc[i][6],acc[i][7]};
            *(float4*)&sm[OFF_XT + (n0+i)*XT_S + h*HD_ + c0] = wa;
            *(float4*)&sm[OFF_XT + (n0+i)*XT_S + h*HD_ + c0 + 4] = wb;
        }
    }
    __syncthreads();

    // ---- P10: out = proj_w @ o + proj_b + x ----
    {
        const int rg = tid >> 3;
        const int vg = tid & 7;
        const int r0 = rg * 4;
        const int v0 = (vg == 0) ? 0 : (3*vg + 1);
        const int nv = (vg == 0) ? 4 : 3;
        float acc[4][4];
        #pragma unroll
        for (int j=0;j<4;++j)
            #pragma unroll
            for (int vv=0;vv<4;++vv) acc[j][vv]=0.f;
        for (int c4 = 0; c4 < C_; c4 += 4) {
            float4 o4[4];
            #pragma unroll
            for (int vv=0;vv<4;++vv)
                o4[vv] = *(const float4*)&sm[OFF_XT + (v0+vv)*XT_S + c4];
            #pragma unroll
            for (int j=0;j<4;++j) {
                float4 w4 = *(const float4*)(pjw + (r0+j)*C_ + c4);
                #pragma unroll
                for (int vv=0;vv<4;++vv)
                    acc[j][vv] += w4.x*o4[vv].x + w4.y*o4[vv].y
                                + w4.z*o4[vv].z + w4.w*o4[vv].w;
            }
        }
        #pragma unroll
        for (int j=0;j<4;++j) {
            int r = r0 + j;
            float pb = pjb[r];
            #pragma unroll
            for (int vv=0;vv<4;++vv) {
                if (vv < nv) {
                    int v = v0 + vv;
                    int idx = xbase + r*TV_ + v;
                    out[idx] = acc[j][vv] + pb + x[idx];
                }
            }
        }
    }
}

extern "C" void kernel_launch(void* const* d_in, const int* in_sizes, int n_in,
                              void* d_out, int out_size, void* d_ws, size_t ws_size,
                              hipStream_t stream) {
    const float* x     = (const float*)d_in[0];
    const float* jl    = (const float*)d_in[1];
    const int*   hops  = (const int*)  d_in[2];
    const float* n1w   = (const float*)d_in[3];
    const float* n1b   = (const float*)d_in[4];
    const float* qw    = (const float*)d_in[5];
    const float* kvw   = (const float*)d_in[6];
    const float* pjw   = (const float*)d_in[7];
    const float* pjb   = (const float*)d_in[8];
    const float* rpe   = (const float*)d_in[9];
    const float* w1    = (const float*)d_in[10];
    const float* outer = (const float*)d_in[11];
    const float* alpha = (const float*)d_in[12];
    const float* pew   = (const float*)d_in[13];
    fused_sttr<<<N_*T_, 512, 0, stream>>>(x, jl, hops, n1w, n1b, qw, kvw,
                                          pjw, pjb, rpe, w1, outer, alpha, pew,
                                          (float*)d_out);
}

// Round 3
// 2569.080 us; speedup vs baseline: 1.5101x; 1.5101x over previous
//
#include <hip/hip_runtime.h>

// Fused ST-attention block for MI355X (gfx950).
// Round 2 (resubmit): weight GEMMs (qkv, proj, pe) on bf16 MFMA with
// split-precision (hi/lo) operands; attention stays fp32 VALU.
// One block per (n,t); 512 threads; ~148.7KB LDS; 1 block/CU.

#define N_ 64
#define C_ 256
#define T_ 120
#define V_ 25
#define H_ 8
#define HD_ 32
#define K_ 5
#define TV_ 3000
#define CTV_ 768000

typedef unsigned short u16;
typedef __bf16 bf16x8 __attribute__((ext_vector_type(8)));
typedef float f32x4 __attribute__((ext_vector_type(4)));
typedef u16 u16x4 __attribute__((ext_vector_type(4)));

#define MFMA(a, b, c) __builtin_amdgcn_mfma_f32_16x16x32_bf16(a, b, c, 0, 0, 0)

__device__ __forceinline__ u16 bhi(float f) {
    union { float f; unsigned u; } c; c.f = f; return (u16)(c.u >> 16);
}
__device__ __forceinline__ float bhif(float f) {
    union { float f; unsigned u; } c; c.f = f; c.u &= 0xFFFF0000u; return c.f;
}

// ---- LDS layout (float-word offsets) ----
#define OFF_XT 0            // [25][268] f32 raw x; later: per-row bf16 hi[256]+lo[256] planes (xn, then o)
#define XT_S 268
#define OFF_Z 6700          // [256][5] f32 z
#define OFF_QB 7980         // [256][28] f32 q; early: zT bf16 planes + Z2 f32
#define OFF_KB 15148        // [256][28] f32 e then k+e
#define OFF_VB 22316        // [8][25][36] f32 v   (P1: PS/PSS overlay)
#define OFF_AT 29516        // [8][25][27] f32 attn/mix
#define AT_S 27
#define OFF_QR 34916        // [8][25][5]
#define OFF_BIAS 35916      // [8][25]
#define OFF_MU 36116
#define OFF_RS 36141
#define OFF_INV 36166
#define OFF_JL 36171        // [25][5]
#define OFF_W1 36296        // [8][32]
#define OFF_HOPS 36552      // int [625]
#define SMEM_N 37177        // 148,708 B
#define OFF_PS OFF_VB
#define OFF_PSS (OFF_VB + 256)
#define OFF_Z2 (OFF_QB + 5120)      // [256][8] f32
// ushort-unit offsets (into smu = (u16*)sm)
#define UZTH (OFF_QB * 2)           // zT hi: [16][264] bf16 (rows 5..15 garbage, cols discarded)
#define UZTL (OFF_QB * 2 + 4224)    // zT lo
// xn/o planes: row v hi at smu[v*536 + c], lo at smu[v*536 + 256 + c]

// ---- ws layout (ushort units): MFMA-swizzled weight fragments ----
// frag(mt,kt,lane): 16 ushorts = hi[8] | lo[8];  elem j -> W[16*mt+(lane&15)][32*kt+8*(lane>>4)+j]
#define WS_Q 0              // 48 mt * 8 kt * 64 * 16 = 393216
#define WS_PE 393216        // 16 mt -> 131072
#define WS_PJ 524288        // 16 mt -> 131072

__global__ __launch_bounds__(256) void wprep(
    const float* __restrict__ qw, const float* __restrict__ kvw,
    const float* __restrict__ pew, const float* __restrict__ pjw,
    u16* __restrict__ ws)
{
    int fid = blockIdx.x * 256 + threadIdx.x;   // 0..40959
    int seg, f;
    if (fid < 24576)      { seg = 0; f = fid; }
    else if (fid < 32768) { seg = 1; f = fid - 24576; }
    else                  { seg = 2; f = fid - 32768; }
    int mt = f >> 9, rem = f & 511, kt = rem >> 6, l = rem & 63;
    int row = mt * 16 + (l & 15);
    int k0 = kt * 32 + (l >> 4) * 8;
    const float* sp;
    u16* dp;
    if (seg == 0) {
        sp = (row < 256) ? (qw + row * 256 + k0) : (kvw + (row - 256) * 256 + k0);
        dp = ws + WS_Q + f * 16;
    } else if (seg == 1) {
        sp = pew + row * 256 + k0;
        dp = ws + WS_PE + f * 16;
    } else {
        sp = pjw + row * 256 + k0;
        dp = ws + WS_PJ + f * 16;
    }
    float4 a = *(const float4*)sp;
    float4 b = *(const float4*)(sp + 4);
    float w8[8] = {a.x, a.y, a.z, a.w, b.x, b.y, b.z, b.w};
    #pragma unroll
    for (int j = 0; j < 8; ++j) {
        float w = w8[j];
        dp[j] = bhi(w);
        dp[8 + j] = bhi(w - bhif(w));
    }
}

__global__ __launch_bounds__(512, 2) void fused_sttr(
    const float* __restrict__ x, const float* __restrict__ jl,
    const int* __restrict__ hops, const float* __restrict__ n1w,
    const float* __restrict__ n1b, const float* __restrict__ rpe,
    const float* __restrict__ pjb, const float* __restrict__ w1,
    const float* __restrict__ outer, const float* __restrict__ alpha,
    const u16* __restrict__ ws, float* __restrict__ out)
{
    __shared__ float sm[SMEM_N];
    u16* smu = reinterpret_cast<u16*>(sm);
    int* hopsS = (int*)(sm + OFF_HOPS);
    const int tid = threadIdx.x;
    const int bid = blockIdx.x;
    const int n = bid / T_;
    const int t = bid - n * T_;
    const int xbase = n * CTV_ + t * V_;
    const u16* wsq = ws + WS_Q;
    const u16* wspe = ws + WS_PE;
    const u16* wspj = ws + WS_PJ;
    const int wv = tid >> 6, ln = tid & 63;
    const int col = ln & 15, kg = ln >> 4;

    // ---- P0: stage tables + x slice (transposed) ----
    for (int i = tid; i < V_ * K_; i += 512) sm[OFF_JL + i] = jl[i];
    for (int i = tid; i < V_ * V_; i += 512) hopsS[i] = hops[i];
    for (int i = tid; i < H_ * HD_; i += 512) sm[OFF_W1 + i] = w1[i];
    for (int i = tid; i < C_ * V_; i += 512) {
        int c = i / V_, v = i - c * V_;
        sm[OFF_XT + v * XT_S + c] = x[xbase + c * TV_ + v];
    }
    __syncthreads();

    // ---- P1: jl column inv-sums | LN partial sums (PS/PSS in VB space) ----
    if (tid < K_) {
        float s = 0.f;
        for (int v = 0; v < V_; ++v) s += sm[OFF_JL + v * K_ + tid];
        sm[OFF_INV + tid] = 1.0f / s;
    } else if (tid >= 256 && tid < 456) {
        int i = tid - 256;
        int v = i % V_, p = i / V_;
        const float* row = &sm[OFF_XT + v * XT_S + p * 32];
        float s = 0.f, ss = 0.f;
        #pragma unroll
        for (int j = 0; j < 32; ++j) { float xx = row[j]; s += xx; ss += xx * xx; }
        sm[OFF_PS + p * 32 + v] = s;
        sm[OFF_PSS + p * 32 + v] = ss;
    }
    __syncthreads();

    // ---- P2: z = x @ (jl/colsum) | mu/rstd ----
    if (tid < C_) {
        float a0 = 0, a1 = 0, a2 = 0, a3 = 0, a4 = 0;
        #pragma unroll
        for (int v = 0; v < V_; ++v) {
            float xv = sm[OFF_XT + v * XT_S + tid];
            const float* j5 = &sm[OFF_JL + v * K_];
            a0 += xv * j5[0]; a1 += xv * j5[1]; a2 += xv * j5[2];
            a3 += xv * j5[3]; a4 += xv * j5[4];
        }
        float* zr = &sm[OFF_Z + tid * K_];
        zr[0] = a0 * sm[OFF_INV + 0]; zr[1] = a1 * sm[OFF_INV + 1];
        zr[2] = a2 * sm[OFF_INV + 2]; zr[3] = a3 * sm[OFF_INV + 3];
        zr[4] = a4 * sm[OFF_INV + 4];
    } else if (tid < C_ + V_) {
        int v = tid - C_;
        float s = 0.f, ss = 0.f;
        #pragma unroll
        for (int p = 0; p < 8; ++p) { s += sm[OFF_PS + p * 32 + v]; ss += sm[OFF_PSS + p * 32 + v]; }
        float mu = s * (1.0f / 256.0f);
        float var = ss * (1.0f / 256.0f) - mu * mu;
        sm[OFF_MU + v] = mu;
        sm[OFF_RS + v] = rsqrtf(var + 1e-5f);
    }
    __syncthreads();

    // ---- P3a: read+normalize xn into regs (200 thr) | write zT bf16 planes (256 thr) ----
    float xr[32];
    {
        if (tid < 200) {
            int v = tid >> 3, cb = tid & 7, c0 = cb * 32;
            float mu = sm[OFF_MU + v], rs = sm[OFF_RS + v];
            #pragma unroll
            for (int j = 0; j < 32; ++j) {
                int c = c0 + j;
                xr[j] = (sm[OFF_XT + v * XT_S + c] - mu) * rs * n1w[c] + n1b[c];
            }
        } else if (tid >= 256) {
            int c = tid - 256;
            #pragma unroll
            for (int nn = 0; nn < K_; ++nn) {
                float f = sm[OFF_Z + c * K_ + nn];
                smu[UZTH + nn * 264 + c] = bhi(f);
                smu[UZTL + nn * 264 + c] = bhi(f - bhif(f));
            }
        }
    }
    __syncthreads();
    // ---- P3b: write xn hi/lo planes in place of XT ----
    if (tid < 200) {
        int v = tid >> 3, cb = tid & 7, c0 = cb * 32;
        #pragma unroll
        for (int jb = 0; jb < 8; ++jb) {
            u16x4 hv, lv;
            #pragma unroll
            for (int j = 0; j < 4; ++j) {
                float f = xr[jb * 4 + j];
                hv[j] = bhi(f);
                lv[j] = bhi(f - bhif(f));
            }
            *(u16x4*)&smu[v * 536 + c0 + jb * 4] = hv;
            *(u16x4*)&smu[v * 536 + 256 + c0 + jb * 4] = lv;
        }
    }
    __syncthreads();

    // ---- P4: pe MFMA: z2 = pew @ z  (A from ws_pe, B from zT) ----
    {
        f32x4 zacc[2];
        #pragma unroll
        for (int i = 0; i < 2; ++i)
            #pragma unroll
            for (int r = 0; r < 4; ++r) zacc[i][r] = 0.f;
        for (int kt = 0; kt < 8; ++kt) {
            int bo = kt * 32 + kg * 8;
            bf16x8 zbh = *reinterpret_cast<const bf16x8*>(&smu[UZTH + col * 264 + bo]);
            bf16x8 zbl = *reinterpret_cast<const bf16x8*>(&smu[UZTL + col * 264 + bo]);
            #pragma unroll
            for (int i = 0; i < 2; ++i) {
                const u16* ap = wspe + (((wv * 2 + i) * 8 + kt) * 64 + ln) * 16;
                bf16x8 ah = *reinterpret_cast<const bf16x8*>(ap);
                bf16x8 al = *reinterpret_cast<const bf16x8*>(ap + 8);
                zacc[i] = MFMA(ah, zbh, zacc[i]);
                zacc[i] = MFMA(ah, zbl, zacc[i]);
                zacc[i] = MFMA(al, zbh, zacc[i]);
            }
        }
        if (col < K_) {
            #pragma unroll
            for (int i = 0; i < 2; ++i)
                #pragma unroll
                for (int r = 0; r < 4; ++r)
                    sm[OFF_Z2 + ((wv * 2 + i) * 16 + kg * 4 + r) * 8 + col] = zacc[i][r];
        }
    }
    __syncthreads();

    // ---- P4b: e = z2 @ jl^T -> KB ----
    if (tid < C_) {
        float z0 = sm[OFF_Z2 + tid * 8 + 0], z1 = sm[OFF_Z2 + tid * 8 + 1];
        float z2_ = sm[OFF_Z2 + tid * 8 + 2], z3 = sm[OFF_Z2 + tid * 8 + 3];
        float z4 = sm[OFF_Z2 + tid * 8 + 4];
        float* kb = &sm[OFF_KB + tid * 28];
        #pragma unroll
        for (int v = 0; v < V_; ++v) {
            const float* j5 = &sm[OFF_JL + v * K_];
            kb[v] = z0 * j5[0] + z1 * j5[1] + z2_ * j5[2] + z3 * j5[3] + z4 * j5[4];
        }
    }
    __syncthreads();

    // ---- P5: qkv MFMA (A=ws_q, B=xn planes); + bias (w1.e) before k-accum ----
    {
        f32x4 acc[6][2];
        #pragma unroll
        for (int i = 0; i < 6; ++i)
            #pragma unroll
            for (int nt = 0; nt < 2; ++nt)
                #pragma unroll
                for (int r = 0; r < 4; ++r) acc[i][nt][r] = 0.f;
        for (int kt = 0; kt < 8; ++kt) {
            int bo = kt * 32 + kg * 8;
            bf16x8 bh0 = *reinterpret_cast<const bf16x8*>(&smu[col * 536 + bo]);
            bf16x8 bl0 = *reinterpret_cast<const bf16x8*>(&smu[col * 536 + 256 + bo]);
            bf16x8 bh1 = *reinterpret_cast<const bf16x8*>(&smu[(col + 16) * 536 + bo]);
            bf16x8 bl1 = *reinterpret_cast<const bf16x8*>(&smu[(col + 16) * 536 + 256 + bo]);
            #pragma unroll
            for (int i = 0; i < 6; ++i) {
                const u16* ap = wsq + (((wv * 6 + i) * 8 + kt) * 64 + ln) * 16;
                bf16x8 ah = *reinterpret_cast<const bf16x8*>(ap);
                bf16x8 al = *reinterpret_cast<const bf16x8*>(ap + 8);
                acc[i][0] = MFMA(ah, bh0, acc[i][0]);
                acc[i][0] = MFMA(ah, bl0, acc[i][0]);
                acc[i][0] = MFMA(al, bh0, acc[i][0]);
                acc[i][1] = MFMA(ah, bh1, acc[i][1]);
                acc[i][1] = MFMA(ah, bl1, acc[i][1]);
                acc[i][1] = MFMA(al, bh1, acc[i][1]);
            }
        }
        // bias[h][m] = w1 . e   (KB still holds pure e)
        if (tid < H_ * V_) {
            int h = tid / V_, m = tid - h * V_;
            float s = 0.f;
            #pragma unroll
            for (int c = 0; c < HD_; ++c)
                s += sm[OFF_W1 + h * HD_ + c] * sm[OFF_KB + (h * HD_ + c) * 28 + m];
            sm[OFF_BIAS + h * V_ + m] = s;
        }
        __syncthreads();
        // writeback q / k+=e / v
        #pragma unroll
        for (int i = 0; i < 6; ++i) {
            #pragma unroll
            for (int nt = 0; nt < 2; ++nt) {
                int v = nt * 16 + col;
                if (v < V_) {
                    #pragma unroll
                    for (int r = 0; r < 4; ++r) {
                        int row = (wv * 6 + i) * 16 + kg * 4 + r;
                        float val = acc[i][nt][r];
                        if (row < 256) sm[OFF_QB + row * 28 + v] = val;
                        else if (row < 512) sm[OFF_KB + (row - 256) * 28 + v] += val;
                        else {
                            int d = row - 512;
                            sm[OFF_VB + ((d >> 5) * V_ + v) * 36 + (d & 31)] = val;
                        }
                    }
                }
            }
        }
    }
    __syncthreads();

    // ---- P6: qr[h][n][hop] = q . rpe  (rpe from global/L2) ----
    for (int i = tid; i < H_ * V_ * K_; i += 512) {
        int h = i / (V_ * K_);
        int rem = i - h * (V_ * K_);
        int nq = rem / K_, hop = rem - nq * K_;
        const float* rp = rpe + hop * 256 + h * HD_;
        float s = 0.f;
        #pragma unroll
        for (int c = 0; c < HD_; ++c)
            s += sm[OFF_QB + (h * HD_ + c) * 28 + nq] * rp[c];
        sm[OFF_QR + (h * V_ + nq) * K_ + hop] = s;
    }
    __syncthreads();

    // ---- P7: attn scores, 4x4 register tiles (392 thr) ----
    if (tid < 392) {
        int h = tid / 49;
        int r = tid - h * 49;
        int qg = r / 7, mg = r - qg * 7;
        int q0 = qg * 4, m0 = mg * 4;
        float acc[4][4];
        #pragma unroll
        for (int i = 0; i < 4; ++i)
            #pragma unroll
            for (int j = 0; j < 4; ++j) acc[i][j] = 0.f;
        for (int c = 0; c < HD_; ++c) {
            float4 q4 = *(const float4*)&sm[OFF_QB + (h * HD_ + c) * 28 + q0];
            float4 k4 = *(const float4*)&sm[OFF_KB + (h * HD_ + c) * 28 + m0];
            float qa[4] = {q4.x, q4.y, q4.z, q4.w};
            float ka[4] = {k4.x, k4.y, k4.z, k4.w};
            #pragma unroll
            for (int i = 0; i < 4; ++i)
                #pragma unroll
                for (int j = 0; j < 4; ++j) acc[i][j] += qa[i] * ka[j];
        }
        #pragma unroll
        for (int i = 0; i < 4; ++i) {
            int nq = q0 + i;
            if (nq < V_) {
                #pragma unroll
                for (int j = 0; j < 4; ++j) {
                    int m = m0 + j;
                    if (m < V_) {
                        int hop = hopsS[nq * V_ + m];
                        sm[OFF_AT + (h * V_ + nq) * AT_S + m] = acc[i][j]
                            + sm[OFF_QR + (h * V_ + nq) * K_ + hop]
                            + sm[OFF_BIAS + h * V_ + m];
                    }
                }
            }
        }
    }
    __syncthreads();

    // ---- P8: softmax + mix = alpha*p + outer (200 thr) ----
    if (tid < H_ * V_) {
        int h = tid / V_, nq = tid - h * V_;
        float* row = &sm[OFF_AT + (h * V_ + nq) * AT_S];
        const float sc = 0.17677669529663688f;
        float ev[25];
        float mx = -1e30f;
        #pragma unroll
        for (int j = 0; j < V_; ++j) { ev[j] = row[j] * sc; mx = fmaxf(mx, ev[j]); }
        float s = 0.f;
        #pragma unroll
        for (int j = 0; j < V_; ++j) { ev[j] = __expf(ev[j] - mx); s += ev[j]; }
        float inv = alpha[0] / s;
        const float* ob = outer + (h * V_ + nq) * V_;
        #pragma unroll
        for (int j = 0; j < V_; ++j) row[j] = ev[j] * inv + ob[j];
    }
    __syncthreads();

    // ---- P9: o = mix @ v -> bf16 hi/lo planes in XT space (320 thr) ----
    if (tid < 320) {
        int h = tid / 40, r = tid % 40, ng = r >> 3, cg = r & 7;
        int n0 = ng * 5, c0 = cg * 4;
        float acc[5][4];
        #pragma unroll
        for (int i = 0; i < 5; ++i)
            #pragma unroll
            for (int j = 0; j < 4; ++j) acc[i][j] = 0.f;
        for (int m = 0; m < V_; ++m) {
            float4 vv = *(const float4*)&sm[OFF_VB + (h * V_ + m) * 36 + c0];
            #pragma unroll
            for (int i = 0; i < 5; ++i) {
                float mx = sm[OFF_AT + (h * V_ + n0 + i) * AT_S + m];
                acc[i][0] += mx * vv.x; acc[i][1] += mx * vv.y;
                acc[i][2] += mx * vv.z; acc[i][3] += mx * vv.w;
            }
        }
        int cb = h * HD_ + c0;
        #pragma unroll
        for (int i = 0; i < 5; ++i) {
            int row = n0 + i;
            u16x4 hv, lv;
            #pragma unroll
            for (int j = 0; j < 4; ++j) {
                float f = acc[i][j];
                hv[j] = bhi(f);
                lv[j] = bhi(f - bhif(f));
            }
            *(u16x4*)&smu[row * 536 + cb] = hv;
            *(u16x4*)&smu[row * 536 + 256 + cb] = lv;
        }
    }
    __syncthreads();

    // ---- P10: proj MFMA (A=ws_pj, B=o planes) + bias + residual ----
    {
        f32x4 pacc[2][2];
        #pragma unroll
        for (int i = 0; i < 2; ++i)
            #pragma unroll
            for (int nt = 0; nt < 2; ++nt)
                #pragma unroll
                for (int r = 0; r < 4; ++r) pacc[i][nt][r] = 0.f;
        for (int kt = 0; kt < 8; ++kt) {
            int bo = kt * 32 + kg * 8;
            bf16x8 oh0 = *reinterpret_cast<const bf16x8*>(&smu[col * 536 + bo]);
            bf16x8 ol0 = *reinterpret_cast<const bf16x8*>(&smu[col * 536 + 256 + bo]);
            bf16x8 oh1 = *reinterpret_cast<const bf16x8*>(&smu[(col + 16) * 536 + bo]);
            bf16x8 ol1 = *reinterpret_cast<const bf16x8*>(&smu[(col + 16) * 536 + 256 + bo]);
            #pragma unroll
            for (int i = 0; i < 2; ++i) {
                const u16* ap = wspj + (((wv * 2 + i) * 8 + kt) * 64 + ln) * 16;
                bf16x8 ah = *reinterpret_cast<const bf16x8*>(ap);
                bf16x8 al = *reinterpret_cast<const bf16x8*>(ap + 8);
                pacc[i][0] = MFMA(ah, oh0, pacc[i][0]);
                pacc[i][0] = MFMA(ah, ol0, pacc[i][0]);
                pacc[i][0] = MFMA(al, oh0, pacc[i][0]);
                pacc[i][1] = MFMA(ah, oh1, pacc[i][1]);
                pacc[i][1] = MFMA(ah, ol1, pacc[i][1]);
                pacc[i][1] = MFMA(al, oh1, pacc[i][1]);
            }
        }
        #pragma unroll
        for (int i = 0; i < 2; ++i) {
            #pragma unroll
            for (int nt = 0; nt < 2; ++nt) {
                int v = nt * 16 + col;
                if (v < V_) {
                    #pragma unroll
                    for (int r = 0; r < 4; ++r) {
                        int row = (wv * 2 + i) * 16 + kg * 4 + r;
                        int idx = xbase + row * TV_ + v;
                        out[idx] = pacc[i][nt][r] + pjb[row] + x[idx];
                    }
                }
            }
        }
    }
}

extern "C" void kernel_launch(void* const* d_in, const int* in_sizes, int n_in,
                              void* d_out, int out_size, void* d_ws, size_t ws_size,
                              hipStream_t stream) {
    const float* x     = (const float*)d_in[0];
    const float* jl    = (const float*)d_in[1];
    const int*   hops  = (const int*)  d_in[2];
    const float* n1w   = (const float*)d_in[3];
    const float* n1b   = (const float*)d_in[4];
    const float* qw    = (const float*)d_in[5];
    const float* kvw   = (const float*)d_in[6];
    const float* pjw   = (const float*)d_in[7];
    const float* pjb   = (const float*)d_in[8];
    const float* rpe   = (const float*)d_in[9];
    const float* w1    = (const float*)d_in[10];
    const float* outer = (const float*)d_in[11];
    const float* alpha = (const float*)d_in[12];
    const float* pew   = (const float*)d_in[13];
    u16* ws = (u16*)d_ws;

    wprep<<<160, 256, 0, stream>>>(qw, kvw, pew, pjw, ws);
    fused_sttr<<<N_ * T_, 512, 0, stream>>>(x, jl, hops, n1w, n1b, rpe, pjb,
                                            w1, outer, alpha, ws, (float*)d_out);
}